// Round 1
// baseline (390.320 us; speedup 1.0000x reference)
//
#include <hip/hip_runtime.h>

#define BATCH 4
#define SEQ   2048
#define EMB   512
#define HEADS 8
#define HD    64

typedef _Float16 half4_t __attribute__((ext_vector_type(4)));
typedef _Float16 half8_t __attribute__((ext_vector_type(8)));
typedef float    f32x4   __attribute__((ext_vector_type(4)));

// ---------------------------------------------------------------- mod factor
__global__ void mod_kernel(const float* __restrict__ emo, float* __restrict__ modv){
    int lane = threadIdx.x;                 // 64 threads, 1 wave
    for (int b = 0; b < BATCH; ++b){
        float v = emo[b*64 + lane];
        #pragma unroll
        for (int off = 32; off >= 1; off >>= 1) v += __shfl_xor(v, off, 64);
        if (lane == 0){
            float mean = v * (1.0f/64.0f);
            float sig  = 1.0f/(1.0f + __expf(-mean));
            modv[b] = 0.5f + 0.5f*sig;
        }
    }
}

__device__ inline half8_t cvt8(const float* p){
    float4 v0 = *(const float4*)p;
    float4 v1 = *(const float4*)(p + 4);
    half8_t r;
    r[0]=(_Float16)v0.x; r[1]=(_Float16)v0.y; r[2]=(_Float16)v0.z; r[3]=(_Float16)v0.w;
    r[4]=(_Float16)v1.x; r[5]=(_Float16)v1.y; r[6]=(_Float16)v1.z; r[7]=(_Float16)v1.w;
    return r;
}

// ------------------------------------------------- QKV projection (f32 -> f16)
// C[m][n] = sum_k X[m][k] * W[n][k] + bias[n]; output head-major f16.
// transposed==0 : out[((b*8+h)*2048+s)*64 + d]   (Q,K layout)
// transposed==1 : out[((b*8+h)*64 + d)*2048 + s] (V^T layout)
__global__ __launch_bounds__(256) void proj_kernel(
    const float* __restrict__ X, const float* __restrict__ W,
    const float* __restrict__ bias, _Float16* __restrict__ out, int transposed)
{
    const int tid  = threadIdx.x;
    const int wid  = tid >> 6;
    const int lane = tid & 63;
    const int l16  = lane & 15;
    const int g    = lane >> 4;
    const int m0 = blockIdx.x*128 + (wid >> 1)*64;
    const int n0 = blockIdx.y*128 + (wid & 1)*64;

    f32x4 acc[4][4] = {};
    for (int kk = 0; kk < 16; ++kk){
        const int k0 = kk*32 + 8*g;
        half8_t a[4], b[4];
        #pragma unroll
        for (int ms = 0; ms < 4; ++ms)
            a[ms] = cvt8(X + (size_t)(m0 + ms*16 + l16)*EMB + k0);
        #pragma unroll
        for (int ns = 0; ns < 4; ++ns)
            b[ns] = cvt8(W + (size_t)(n0 + ns*16 + l16)*EMB + k0);
        #pragma unroll
        for (int ms = 0; ms < 4; ++ms)
            #pragma unroll
            for (int ns = 0; ns < 4; ++ns)
                acc[ms][ns] = __builtin_amdgcn_mfma_f32_16x16x32_f16(a[ms], b[ns], acc[ms][ns], 0, 0, 0);
    }
    #pragma unroll
    for (int ns = 0; ns < 4; ++ns){
        const int n  = n0 + ns*16 + l16;
        const float bn = bias[n];
        const int h = n >> 6, d = n & 63;
        #pragma unroll
        for (int ms = 0; ms < 4; ++ms){
            #pragma unroll
            for (int r = 0; r < 4; ++r){
                const int m  = m0 + ms*16 + 4*g + r;
                const int bb = m >> 11, s = m & 2047;
                const float v = acc[ms][ns][r] + bn;
                size_t idx = transposed ? ((size_t)((bb*8 + h)*64 + d)*SEQ + s)
                                        : ((size_t)((bb*8 + h)*SEQ + s)*64 + d);
                out[idx] = (_Float16)v;
            }
        }
    }
}

// ------------------------------------------------------------ fused attention
// 8 waves/block, wave = head. 32 q-rows per block. Two passes over keys:
// pass 1: softmax denominators (sum of exp, logits bounded -> no max shift)
// pass 2: recompute QK, p = exp*inv_l, PV mfma (p regs feed 16x16x16 A directly),
//         cross-head mean via LDS (row stride 19 to kill bank conflicts).
__global__ __launch_bounds__(512) void attn_kernel(
    const _Float16* __restrict__ Qp, const _Float16* __restrict__ Kp,
    const _Float16* __restrict__ Vt, const float* __restrict__ emo_bias,
    const float* __restrict__ modv, _Float16* __restrict__ attended,
    float* __restrict__ mean_out)
{
    __shared__ float lds[HEADS * 32 * 19];
    const int tid  = threadIdx.x;
    const int h    = tid >> 6;          // wave index = head
    const int lane = tid & 63;
    const int l16  = lane & 15;
    const int g    = lane >> 4;
    const int b    = blockIdx.x >> 6;   // 64 q-tiles per batch
    const int qt   = blockIdx.x & 63;
    const int q0   = qt * 32;

    const float mod = modv[b];
    const float sm  = 0.125f * mod;       // scale * mod
    const float bm  = emo_bias[h] * mod;  // bias  * mod

    const size_t headOff = (size_t)(b*HEADS + h) * SEQ * HD;
    const _Float16* Qh = Qp + headOff;
    const _Float16* Kh = Kp + headOff;
    const _Float16* Vh = Vt + headOff;    // [HD][SEQ]

    // persistent Q fragments: [sub][chunk], d = 32c + 8g + i
    half8_t qf[2][2];
    #pragma unroll
    for (int sub = 0; sub < 2; ++sub)
        #pragma unroll
        for (int c = 0; c < 2; ++c)
            qf[sub][c] = *(const half8_t*)(Qh + (size_t)(q0 + sub*16 + l16)*HD + c*32 + 8*g);

    // ---- pass 1: denominators
    float lsum[2] = {0.f, 0.f};
    for (int kt = 0; kt < SEQ/16; ++kt){
        const int k0 = kt * 16;
        half8_t kf[2];
        #pragma unroll
        for (int c = 0; c < 2; ++c)
            kf[c] = *(const half8_t*)(Kh + (size_t)(k0 + l16)*HD + c*32 + 8*g);
        #pragma unroll
        for (int sub = 0; sub < 2; ++sub){
            f32x4 s = {};
            s = __builtin_amdgcn_mfma_f32_16x16x32_f16(kf[0], qf[sub][0], s, 0, 0, 0);
            s = __builtin_amdgcn_mfma_f32_16x16x32_f16(kf[1], qf[sub][1], s, 0, 0, 0);
            float e0 = __expf(s[0]*sm + bm);
            float e1 = __expf(s[1]*sm + bm);
            float e2 = __expf(s[2]*sm + bm);
            float e3 = __expf(s[3]*sm + bm);
            lsum[sub] += (e0 + e1) + (e2 + e3);
        }
    }
    #pragma unroll
    for (int sub = 0; sub < 2; ++sub){
        float v = lsum[sub];
        v += __shfl_xor(v, 16, 64);
        v += __shfl_xor(v, 32, 64);
        lsum[sub] = 1.0f / v;             // inv denominator, same in all 4 g-lanes
    }

    // ---- pass 2: PV + mean
    f32x4 acc[2][4] = {};                 // [sub][d-chunk]
    for (int kt = 0; kt < SEQ/16; ++kt){
        const int k0 = kt * 16;
        half8_t kf[2];
        #pragma unroll
        for (int c = 0; c < 2; ++c)
            kf[c] = *(const half8_t*)(Kh + (size_t)(k0 + l16)*HD + c*32 + 8*g);
        half4_t vf[4];                    // B-frag: elem i -> key k0+4g+i, col d=16c+l16
        #pragma unroll
        for (int c = 0; c < 4; ++c)
            vf[c] = *(const half4_t*)(Vh + (size_t)(16*c + l16)*SEQ + k0 + 4*g);

        float p[2][4];
        #pragma unroll
        for (int sub = 0; sub < 2; ++sub){
            f32x4 s = {};
            s = __builtin_amdgcn_mfma_f32_16x16x32_f16(kf[0], qf[sub][0], s, 0, 0, 0);
            s = __builtin_amdgcn_mfma_f32_16x16x32_f16(kf[1], qf[sub][1], s, 0, 0, 0);
            #pragma unroll
            for (int r = 0; r < 4; ++r)
                p[sub][r] = __expf(s[r]*sm + bm) * lsum[sub];
        }
        // stage p for the head-mean (q rows stride 19 -> conflict-light)
        #pragma unroll
        for (int sub = 0; sub < 2; ++sub)
            #pragma unroll
            for (int r = 0; r < 4; ++r)
                lds[h*608 + (sub*16 + l16)*19 + 4*g + r] = p[sub][r];
        // PV: p regs are exactly the 16x16x16 A-fragment (row=l16=q, k=4g+i=key)
        #pragma unroll
        for (int sub = 0; sub < 2; ++sub){
            half4_t pf;
            pf[0]=(_Float16)p[sub][0]; pf[1]=(_Float16)p[sub][1];
            pf[2]=(_Float16)p[sub][2]; pf[3]=(_Float16)p[sub][3];
            #pragma unroll
            for (int c = 0; c < 4; ++c)
                acc[sub][c] = __builtin_amdgcn_mfma_f32_16x16x16f16(pf, vf[c], acc[sub][c], 0, 0, 0);
        }
        __syncthreads();
        {   // deterministic cross-head sum; coalesced 16-float rows
            const int q = tid >> 4, k = tid & 15;
            float ssum = 0.f;
            #pragma unroll
            for (int hh = 0; hh < HEADS; ++hh) ssum += lds[hh*608 + q*19 + k];
            mean_out[((size_t)(b*SEQ + q0 + q))*SEQ + k0 + k] = ssum * (1.0f/HEADS);
        }
        __syncthreads();
    }

    // attended store: lane holds q = q0+16sub+4g+r, e = h*64 + 16c + l16
    #pragma unroll
    for (int sub = 0; sub < 2; ++sub)
        #pragma unroll
        for (int c = 0; c < 4; ++c)
            #pragma unroll
            for (int r = 0; r < 4; ++r){
                const int q = q0 + sub*16 + 4*g + r;
                const int e = h*64 + 16*c + l16;
                attended[(size_t)(b*SEQ + q)*EMB + e] = (_Float16)acc[sub][c][r];
            }
}

// ------------------------------------------------------ output projection f32
__global__ __launch_bounds__(256) void outproj_kernel(
    const _Float16* __restrict__ A, const float* __restrict__ W,
    const float* __restrict__ bias, float* __restrict__ out)
{
    const int tid  = threadIdx.x;
    const int wid  = tid >> 6;
    const int lane = tid & 63;
    const int l16  = lane & 15;
    const int g    = lane >> 4;
    const int m0 = blockIdx.x*128 + (wid >> 1)*64;
    const int n0 = blockIdx.y*128 + (wid & 1)*64;

    f32x4 acc[4][4] = {};
    for (int kk = 0; kk < 16; ++kk){
        const int k0 = kk*32 + 8*g;
        half8_t a[4], b[4];
        #pragma unroll
        for (int ms = 0; ms < 4; ++ms)
            a[ms] = *(const half8_t*)(A + (size_t)(m0 + ms*16 + l16)*EMB + k0);
        #pragma unroll
        for (int ns = 0; ns < 4; ++ns)
            b[ns] = cvt8(W + (size_t)(n0 + ns*16 + l16)*EMB + k0);
        #pragma unroll
        for (int ms = 0; ms < 4; ++ms)
            #pragma unroll
            for (int ns = 0; ns < 4; ++ns)
                acc[ms][ns] = __builtin_amdgcn_mfma_f32_16x16x32_f16(a[ms], b[ns], acc[ms][ns], 0, 0, 0);
    }
    #pragma unroll
    for (int ns = 0; ns < 4; ++ns){
        const int n = n0 + ns*16 + l16;
        const float bn = bias[n];
        #pragma unroll
        for (int ms = 0; ms < 4; ++ms)
            #pragma unroll
            for (int r = 0; r < 4; ++r){
                const int m = m0 + ms*16 + 4*g + r;
                out[(size_t)m*EMB + n] = acc[ms][ns][r] + bn;
            }
    }
}

// ---------------------------------------------------------------------- host
extern "C" void kernel_launch(void* const* d_in, const int* in_sizes, int n_in,
                              void* d_out, int out_size, void* d_ws, size_t ws_size,
                              hipStream_t stream)
{
    const float* query = (const float*)d_in[0];
    const float* key_  = (const float*)d_in[1];
    const float* value = (const float*)d_in[2];
    const float* emo   = (const float*)d_in[3];
    const float* Wq = (const float*)d_in[4];
    const float* bq = (const float*)d_in[5];
    const float* Wk = (const float*)d_in[6];
    const float* bk = (const float*)d_in[7];
    const float* Wv = (const float*)d_in[8];
    const float* bv = (const float*)d_in[9];
    const float* Wo = (const float*)d_in[10];
    const float* bo = (const float*)d_in[11];
    const float* emo_bias = (const float*)d_in[12];

    const size_t NTOK = (size_t)BATCH * SEQ * EMB;   // 4,194,304
    _Float16* ws       = (_Float16*)d_ws;
    _Float16* Qp       = ws;
    _Float16* Kp       = ws + NTOK;
    _Float16* Vt       = ws + 2*NTOK;
    _Float16* attended = ws + 3*NTOK;
    float*    modv     = (float*)(ws + 4*NTOK);

    float* out0     = (float*)d_out;
    float* mean_out = out0 + NTOK;

    mod_kernel<<<1, 64, 0, stream>>>(emo, modv);
    dim3 pg(64, 4);
    proj_kernel<<<pg, 256, 0, stream>>>(query, Wq, bq, Qp, 0);
    proj_kernel<<<pg, 256, 0, stream>>>(key_,  Wk, bk, Kp, 0);
    proj_kernel<<<pg, 256, 0, stream>>>(value, Wv, bv, Vt, 1);
    attn_kernel<<<BATCH * (SEQ/32), 512, 0, stream>>>(Qp, Kp, Vt, emo_bias, modv, attended, mean_out);
    outproj_kernel<<<pg, 256, 0, stream>>>(attended, Wo, bo, out0);
}